// Round 7
// baseline (417.284 us; speedup 1.0000x reference)
//
#include <hip/hip_runtime.h>

typedef unsigned int   u32;
typedef unsigned short u16;

#define HW 262144   // 512*512
#define W512 512

__device__ __forceinline__ u32 f2b_rtne(float f) {   // f32 -> bf16 bits (RTNE)
    union { float f; u32 i; } c; c.f = f;
    u32 u = c.i;
    return (u + 0x7FFFu + ((u >> 16) & 1u)) >> 16;
}
__device__ __forceinline__ float lo16(u32 w) {       // low bf16 of packed pair
    union { u32 i; float f; } c; c.i = w << 16; return c.f;
}
__device__ __forceinline__ float hi16(u32 w) {       // high bf16 of packed pair
    union { u32 i; float f; } c; c.i = w & 0xFFFF0000u; return c.f;
}

// ---------------------------------------------------------------------------
// k_band: metrics over a horizontal band. nb bands/batch (32 fast, 1 slow).
// ---------------------------------------------------------------------------
__global__ __launch_bounds__(1024) void k_band(
    const float* __restrict__ ev, const float* __restrict__ fr,
    int nb, float* __restrict__ partials, float* __restrict__ z)
{
    __shared__ float sY[18][512];
    __shared__ float sE[18][512];
    __shared__ float cellPart[1024];
    __shared__ float cellFull[256];
    __shared__ float red[16][8];

    int blk = blockIdx.x;
    int b = blk / nb, band = blk % nb;
    int rowsPerBand = 512 / nb;
    int chunks = rowsPerBand >> 4;
    int rBase = band * rowsPerBand;
    int tid = threadIdx.x;

    const float* Pp = ev + (size_t)(b * 2)     * HW;
    const float* Np = ev + (size_t)(b * 2 + 1) * HW;
    const float* Rp = fr + (size_t)(b * 3)     * HW;
    const float* Gp = fr + (size_t)(b * 3 + 1) * HW;
    const float* Bp = fr + (size_t)(b * 3 + 2) * HW;

    if (nb == 1 && tid < 256) cellFull[tid] = 0.f;

    float aY = 0, aY2 = 0, aL = 0, aL2 = 0, aG = 0, aPb = 0, aLE = 0, aLE2 = 0;

    for (int ch = 0; ch < chunks; ++ch) {
        int r0 = rBase + ch * 16;
        for (int idx = tid; idx < 18 * 512; idx += 1024) {
            int rl = idx >> 9, c = idx & 511;
            int gy = r0 - 1 + rl;
            float y = 0.f, e = 0.f;
            if (gy >= 0 && gy < W512) {
                size_t o = (size_t)gy * W512 + c;
                float rr = Rp[o], gg = Gp[o], bb = Bp[o];
                y = fminf(fmaxf(0.299f * rr + 0.587f * gg + 0.114f * bb, 0.f), 1.f);
                e = fmaxf((Pp[o] + Np[o]) * (1.f / 255.f), 0.f);
            }
            sY[rl][c] = y; sE[rl][c] = e;
        }
        __syncthreads();

        float ce = 0.f;
        int hf = tid >> 9, col = tid & 511;
        for (int i = 0; i < 8; ++i) {
            int rl = hf + 2 * i;
            int lr = rl + 1;
            int gy = r0 + rl;
            float y   = sY[lr][col];
            float yu  = sY[lr - 1][col], yd = sY[lr + 1][col];
            float yl  = col        ? sY[lr][col - 1]     : 0.f;
            float yr  = col < 511  ? sY[lr][col + 1]     : 0.f;
            float yul = col        ? sY[lr - 1][col - 1] : 0.f;
            float yur = col < 511  ? sY[lr - 1][col + 1] : 0.f;
            float ydl = col        ? sY[lr + 1][col - 1] : 0.f;
            float ydr = col < 511  ? sY[lr + 1][col + 1] : 0.f;
            float lap = yu + yd + yl + yr - 4.f * y;
            float gx  = (yur + 2.f * yr + ydr) - (yul + 2.f * yl + ydl);
            float gy2 = (ydl + 2.f * yd + ydr) - (yul + 2.f * yu + yur);
            float gm  = sqrtf(gx * gx + gy2 * gy2);
            float e   = sE[lr][col];
            float el  = col       ? sE[lr][col - 1] : 0.f;
            float er  = col < 511 ? sE[lr][col + 1] : 0.f;
            float lapE = sE[lr - 1][col] + sE[lr + 1][col] + el + er - 4.f * e;
            size_t o = (size_t)gy * W512 + col;
            float pn = Pp[o] * (1.f / 255.f);
            float nn = Np[o] * (1.f / 255.f);
            float pb = (pn - nn) / (pn + nn + 1e-12f);
            aY += y; aY2 += y * y; aL += lap; aL2 += lap * lap; aG += gm;
            aPb += pb; aLE += lapE; aLE2 += lapE * lapE; ce += e;
        }
        cellPart[tid] = ce;
        __syncthreads();
        if (tid < 16) {
            float s = 0.f;
            int c0 = tid * 32;
            for (int h2 = 0; h2 < 2; ++h2)
                for (int c = 0; c < 32; ++c) s += cellPart[h2 * 512 + c0 + c];
            if (nb == 1) cellFull[(r0 >> 5) * 16 + tid] += s;
            else         partials[(size_t)blk * 32 + 9 + tid] = s;
        }
        __syncthreads();
    }

    float v[8] = {aY, aY2, aL, aL2, aG, aPb, aLE, aLE2};
    #pragma unroll
    for (int off = 32; off; off >>= 1)
        #pragma unroll
        for (int k = 0; k < 8; ++k) v[k] += __shfl_down(v[k], off);
    int lane = tid & 63, wid = tid >> 6;
    if (lane == 0)
        for (int k = 0; k < 8; ++k) red[wid][k] = v[k];
    __syncthreads();

    if (tid == 0) {
        float s[8];
        for (int k = 0; k < 8; ++k) {
            float t = 0.f;
            for (int w = 0; w < 16; ++w) t += red[w][k];
            s[k] = t;
        }
        if (nb > 1) {
            float* rec = partials + (size_t)blk * 32;
            for (int k = 0; k < 8; ++k) rec[k] = s[k];
        } else {
            float c1 = 0.f, c2 = 0.f, ct = 0.f;
            for (int j = 0; j < 256; ++j) {
                float m = cellFull[j] * (1.f / 1024.f);
                c1 += m; c2 += m * m; ct += cellFull[j];
            }
            const float FN = 262144.f;
            float muY   = s[0] / FN;
            float stdY  = sqrtf(fmaxf(s[1] / FN - muY * muY, 0.f));
            float varlp = fmaxf(s[3] - s[2] * s[2] / FN, 0.f) / (FN - 1.f);
            float gmean = s[4] / FN;
            float mc = c1 * (1.f / 256.f);
            float vc = fmaxf(c2 * (1.f / 256.f) - mc * mc, 0.f);
            float cv = sqrtf(vc) / (mc + 1e-12f);
            float dens = ct / FN;
            float pb = s[5] / FN;
            float varlpE = fmaxf(s[7] - s[6] * s[6] / FN, 0.f) / (FN - 1.f);
            float* zb = z + b * 8;
            zb[0] = muY; zb[1] = stdY; zb[2] = varlp; zb[3] = gmean;
            zb[4] = cv;  zb[5] = dens; zb[6] = pb;    zb[7] = varlpE;
        }
    }
}

// ---------------------------------------------------------------------------
// k_finalize (fast path): merge 32 band records per batch -> z[16][8]
// ---------------------------------------------------------------------------
__global__ __launch_bounds__(256) void k_finalize(
    const float* __restrict__ partials, float* __restrict__ z)
{
    __shared__ float sred[8];
    __shared__ float rr[4][3];
    int b = blockIdx.x, tid = threadIdx.x;
    if (tid < 8) {
        float s = 0.f;
        for (int band = 0; band < 32; ++band)
            s += partials[(size_t)(b * 32 + band) * 32 + tid];
        sred[tid] = s;
    }
    int cr = tid >> 4, cc = tid & 15;
    float cell = partials[(size_t)(b * 32 + 2 * cr)     * 32 + 9 + cc]
               + partials[(size_t)(b * 32 + 2 * cr + 1) * 32 + 9 + cc];
    float m = cell * (1.f / 1024.f);
    float c1 = m, c2 = m * m, ct = cell;
    #pragma unroll
    for (int off = 32; off; off >>= 1) {
        c1 += __shfl_down(c1, off);
        c2 += __shfl_down(c2, off);
        ct += __shfl_down(ct, off);
    }
    int lane = tid & 63, wid = tid >> 6;
    if (lane == 0) { rr[wid][0] = c1; rr[wid][1] = c2; rr[wid][2] = ct; }
    __syncthreads();
    if (tid == 0) {
        float C1 = rr[0][0] + rr[1][0] + rr[2][0] + rr[3][0];
        float C2 = rr[0][1] + rr[1][1] + rr[2][1] + rr[3][1];
        float CT = rr[0][2] + rr[1][2] + rr[2][2] + rr[3][2];
        const float FN = 262144.f;
        float muY   = sred[0] / FN;
        float stdY  = sqrtf(fmaxf(sred[1] / FN - muY * muY, 0.f));
        float varlp = fmaxf(sred[3] - sred[2] * sred[2] / FN, 0.f) / (FN - 1.f);
        float gmean = sred[4] / FN;
        float mc = C1 * (1.f / 256.f);
        float vc = fmaxf(C2 * (1.f / 256.f) - mc * mc, 0.f);
        float cv = sqrtf(vc) / (mc + 1e-12f);
        float dens = CT / FN;
        float pb = sred[5] / FN;
        float varlpE = fmaxf(sred[7] - sred[6] * sred[6] / FN, 0.f) / (FN - 1.f);
        float* zb = z + b * 8;
        zb[0] = muY; zb[1] = stdY; zb[2] = varlp; zb[3] = gmean;
        zb[4] = cv;  zb[5] = dens; zb[6] = pb;    zb[7] = varlpE;
    }
}

// ---------------------------------------------------------------------------
// k_mlp: metrics MLP -> per (batch, channel) affine coefs. 1 block, (64,16)
// ---------------------------------------------------------------------------
__global__ __launch_bounds__(1024) void k_mlp(
    const float* __restrict__ z,
    const float* __restrict__ w1, const float* __restrict__ b1,
    const float* __restrict__ w2, const float* __restrict__ b2,
    const float* __restrict__ hgw, const float* __restrict__ hgb,
    const float* __restrict__ hfw, const float* __restrict__ hfb,
    const float* __restrict__ rs,
    float* __restrict__ coefA, float* __restrict__ coefB)
{
    __shared__ float sZ[16][8], sH1[16][64], sH2[16][64], sG[16][2], sF[16][10];
    int j = threadIdx.x, b = threadIdx.y;
    if (j < 8) sZ[b][j] = z[b * 8 + j];
    __syncthreads();
    float a = b1[j];
    #pragma unroll
    for (int k = 0; k < 8; ++k) a += sZ[b][k] * w1[j * 8 + k];
    sH1[b][j] = fmaxf(a, 0.f);
    __syncthreads();
    float a2 = b2[j];
    for (int k = 0; k < 64; ++k) a2 += sH1[b][k] * w2[j * 64 + k];
    sH2[b][j] = fmaxf(a2, 0.f);
    __syncthreads();
    if (j < 2) {
        float g = hgb[j];
        for (int k = 0; k < 64; ++k) g += sH2[b][k] * hgw[j * 64 + k];
        sG[b][j] = 1.f / (1.f + __expf(-g));
    }
    if (j < 10) {
        float f = hfb[j];
        for (int k = 0; k < 64; ++k) f += sH2[b][k] * hfw[j * 64 + k];
        sF[b][j] = f;
    }
    __syncthreads();
    if (j < 5) {
        float gs = sG[b][0] + sG[b][1] + 1e-12f;
        float alpha = (j < 2 ? sG[b][0] : sG[b][1]) / gs;
        float gamma = 1.f + 0.1f * sF[b][j];
        float beta  = 0.1f * sF[b][5 + j];
        float r = rs[0];
        coefA[b * 5 + j] = r * alpha * gamma;
        coefB[b * 5 + j] = r * alpha * beta;
    }
}

// ---------------------------------------------------------------------------
// k_main: fused conv1+bn1+silu+conv2+bn2 + FiLM + residual (f32 out).
// grid (16,16,16), 320 threads, 32x32 tile per block.
//  - sIn/sT1 stored as packed bf16 pairs (u32): LDS 42 KB -> 3 blocks/CU
//    (was 78.5 KB -> 2 blocks/CU). bf16 error only enters the fused branch,
//    scaled by ~res_scale*alpha*gamma (~0.05) => ~3e-4 output error.
//  - 320 threads: conv1's 306 strips complete in ONE pass (no wave-0 tail).
//  - residual re-read from global as exact f32 (L2-hot tile).
// ---------------------------------------------------------------------------
__global__ __launch_bounds__(320, 4) void k_main(
    const float* __restrict__ ev, const float* __restrict__ fr,
    const float* __restrict__ c1w,
    const float* __restrict__ bn1g, const float* __restrict__ bn1b,
    const float* __restrict__ bn1m, const float* __restrict__ bn1v,
    const float* __restrict__ c2w,
    const float* __restrict__ bn2g, const float* __restrict__ bn2b,
    const float* __restrict__ bn2m, const float* __restrict__ bn2v,
    const float* __restrict__ coefA, const float* __restrict__ coefB,
    float* __restrict__ out)
{
    __shared__ u32 sIn[5][36][20];     // bf16-pair tile, 14.4 KB
    __shared__ u32 sT1[8][34][20];     // bf16-pair conv1 half-output, 21.76 KB
    __shared__ float sW1[45 * 16];     // folded conv1 weights [tap][oc]
    __shared__ float sW2[144 * 5];     // folded conv2 weights [tap][oc]
    __shared__ float sB1[16];
    __shared__ float sB2[5];

    int tid = threadIdx.x;
    int b = blockIdx.z;
    int ty0 = blockIdx.y * 32, tx0 = blockIdx.x * 32;

    for (int t = tid; t < 720; t += 320) {
        int tap = t >> 4, oc = t & 15;
        float inv = bn1g[oc] * rsqrtf(bn1v[oc] + 1e-5f);
        sW1[tap * 16 + oc] = c1w[oc * 45 + tap] * inv;
    }
    for (int t = tid; t < 720; t += 320) {
        int tap = t / 5, oc = t % 5;
        float inv = bn2g[oc] * rsqrtf(bn2v[oc] + 1e-5f);
        sW2[t] = c2w[oc * 144 + tap] * inv;
    }
    if (tid < 16) {
        float inv = bn1g[tid] * rsqrtf(bn1v[tid] + 1e-5f);
        sB1[tid] = bn1b[tid] - bn1m[tid] * inv;
    }
    if (tid >= 32 && tid < 37) {
        int oc = tid - 32;
        float inv = bn2g[oc] * rsqrtf(bn2v[oc] + 1e-5f);
        sB2[oc] = bn2b[oc] - bn2m[oc] * inv;
    }

    // stage input tile as bf16 pairs (3600 u32)
    for (int idx = tid; idx < 3600; idx += 320) {
        int chn = idx / 720, rem = idx % 720;
        int r = rem / 20, cc = rem % 20;
        int gy = ty0 - 2 + r, gx = tx0 - 2 + 2 * cc;
        float v0 = 0.f, v1 = 0.f;
        if (gy >= 0 && gy < W512 && 2 * cc < 36) {
            const float* src = (chn < 2) ? (ev + (size_t)(b * 2 + chn) * HW)
                                         : (fr + (size_t)(b * 3 + chn - 2) * HW);
            size_t o = (size_t)gy * W512;
            if (gx >= 0 && gx < W512)         v0 = src[o + gx];
            if (gx + 1 >= 0 && gx + 1 < W512) v1 = src[o + gx + 1];
        }
        sIn[chn][r][cc] = f2b_rtne(v0) | (f2b_rtne(v1) << 16);
    }
    __syncthreads();

    int pr = tid >> 3, pc0 = (tid & 7) << 2, pcu = (tid & 7) << 1;
    float acc2[5][4];
    #pragma unroll
    for (int oc = 0; oc < 5; ++oc)
        #pragma unroll
        for (int p = 0; p < 4; ++p) acc2[oc][p] = sB2[oc];

    #pragma unroll 1
    for (int h = 0; h < 2; ++h) {
        // ---- conv1 (+bn1+silu) for oc h*8..h*8+7, single pass (306<=320) ----
        if (tid < 306) {
            int s = tid;
            int r = s / 9, cu = (s % 9) * 2;
            float acc[8][4];
            #pragma unroll
            for (int oc = 0; oc < 8; ++oc) {
                float bb = sB1[h * 8 + oc];
                #pragma unroll
                for (int p = 0; p < 4; ++p) acc[oc][p] = bb;
            }
            #pragma unroll 1
            for (int t = 0; t < 15; ++t) {
                const u32* rp = &sIn[t / 3][r + (t % 3)][cu];
                u32 w0 = rp[0], w1 = rp[1], w2 = rp[2];
                float x[6];
                x[0] = lo16(w0); x[1] = hi16(w0);
                x[2] = lo16(w1); x[3] = hi16(w1);
                x[4] = lo16(w2); x[5] = hi16(w2);
                #pragma unroll
                for (int dx = 0; dx < 3; ++dx) {
                    const float* wv = &sW1[(t * 3 + dx) * 16 + h * 8];
                    #pragma unroll
                    for (int oc = 0; oc < 8; ++oc) {
                        float w = wv[oc];
                        #pragma unroll
                        for (int p = 0; p < 4; ++p) acc[oc][p] += x[dx + p] * w;
                    }
                }
            }
            int gy1 = ty0 - 1 + r;
            bool rowok = (gy1 >= 0 && gy1 < W512);
            int c0 = cu * 2;
            #pragma unroll
            for (int oc = 0; oc < 8; ++oc) {
                float sl[4];
                #pragma unroll
                for (int p = 0; p < 4; ++p) {
                    float vv = acc[oc][p];
                    float s2 = vv / (1.f + __expf(-vv));
                    int gx1 = tx0 - 1 + c0 + p;
                    // conv2's SAME padding sees ZEROS outside image
                    if (!rowok || gx1 < 0 || gx1 >= W512) s2 = 0.f;
                    sl[p] = s2;
                }
                sT1[oc][r][cu]     = f2b_rtne(sl[0]) | (f2b_rtne(sl[1]) << 16);
                sT1[oc][r][cu + 1] = f2b_rtne(sl[2]) | (f2b_rtne(sl[3]) << 16);
            }
        }
        __syncthreads();

        // ---- conv2 partial accumulation over this half's 8 input channels ----
        if (tid < 256) {
            #pragma unroll 1
            for (int t = 0; t < 24; ++t) {          // t = ic*3 + dy
                const u32* rp = &sT1[t / 3][pr + (t % 3)][pcu];
                u32 w0 = rp[0], w1 = rp[1], w2 = rp[2];
                float x[6];
                x[0] = lo16(w0); x[1] = hi16(w0);
                x[2] = lo16(w1); x[3] = hi16(w1);
                x[4] = lo16(w2); x[5] = hi16(w2);
                #pragma unroll
                for (int dx = 0; dx < 3; ++dx) {
                    const float* wv = &sW2[((h * 8 + t / 3) * 9 + (t % 3) * 3 + dx) * 5];
                    #pragma unroll
                    for (int oc = 0; oc < 5; ++oc) {
                        float w = wv[oc];
                        #pragma unroll
                        for (int p = 0; p < 4; ++p) acc2[oc][p] += x[dx + p] * w;
                    }
                }
            }
        }
        __syncthreads();   // before next h overwrites sT1
    }

    if (tid < 256) {
        float cA[5], cB[5];
        #pragma unroll
        for (int oc = 0; oc < 5; ++oc) {
            cA[oc] = coefA[b * 5 + oc];
            cB[oc] = coefB[b * 5 + oc];
        }
        int gy = ty0 + pr, gx0 = tx0 + pc0;
        #pragma unroll
        for (int oc = 0; oc < 5; ++oc) {
            // residual from global (exact f32, L2-hot)
            size_t ioff;
            const float* src;
            if (oc < 2) { src = ev; ioff = (size_t)(b * 2 + oc) * HW; }
            else        { src = fr; ioff = (size_t)(b * 3 + oc - 2) * HW; }
            float4 iv = *reinterpret_cast<const float4*>(&src[ioff + (size_t)gy * W512 + gx0]);
            float4 pk;
            pk.x = iv.x + cA[oc] * acc2[oc][0] + cB[oc];
            pk.y = iv.y + cA[oc] * acc2[oc][1] + cB[oc];
            pk.z = iv.z + cA[oc] * acc2[oc][2] + cB[oc];
            pk.w = iv.w + cA[oc] * acc2[oc][3] + cB[oc];
            size_t off;
            if (oc < 2) off = (size_t)(b * 2 + oc) * HW + (size_t)gy * W512 + gx0;
            else        off = (size_t)2 * 16 * HW + (size_t)(b * 3 + oc - 2) * HW + (size_t)gy * W512 + gx0;
            *reinterpret_cast<float4*>(out + off) = pk;
        }
    }
}

// ---------------------------------------------------------------------------
extern "C" void kernel_launch(void* const* d_in, const int* in_sizes, int n_in,
                              void* d_out, int out_size, void* d_ws, size_t ws_size,
                              hipStream_t stream)
{
    const float* ev = (const float*)d_in[0];
    const float* fr = (const float*)d_in[1];

    float* ws = (float*)d_ws;
    float* coefA    = ws;           // 80
    float* coefB    = ws + 80;      // 80
    float* zbuf     = ws + 256;     // 128
    float* partials = ws + 1024;    // 512*32 = 16384 floats (fast path)

    bool fast = (ws_size >= 69632 + 4096);
    int nb   = fast ? 32 : 1;
    int nblk = fast ? 512 : 16;
    k_band<<<dim3(nblk), dim3(1024), 0, stream>>>(ev, fr, nb, partials, zbuf);
    if (fast) k_finalize<<<dim3(16), dim3(256), 0, stream>>>(partials, zbuf);

    k_mlp<<<dim3(1), dim3(64, 16), 0, stream>>>(zbuf,
        (const float*)d_in[12], (const float*)d_in[13], (const float*)d_in[14], (const float*)d_in[15],
        (const float*)d_in[16], (const float*)d_in[17], (const float*)d_in[18], (const float*)d_in[19],
        (const float*)d_in[20], coefA, coefB);

    k_main<<<dim3(16, 16, 16), dim3(320), 0, stream>>>(ev, fr,
        (const float*)d_in[2], (const float*)d_in[3], (const float*)d_in[4], (const float*)d_in[5],
        (const float*)d_in[6], (const float*)d_in[7], (const float*)d_in[8], (const float*)d_in[9],
        (const float*)d_in[10], (const float*)d_in[11],
        coefA, coefB, (float*)d_out);
}

// Round 8
// 331.918 us; speedup vs baseline: 1.2572x; 1.2572x over previous
//
#include <hip/hip_runtime.h>

typedef unsigned int u32;

#define HW 262144   // 512*512
#define W512 512

__device__ __forceinline__ u32 f2b_rtne(float f) {   // f32 -> bf16 bits (RTNE)
    union { float f; u32 i; } c; c.f = f;
    u32 u = c.i;
    return (u + 0x7FFFu + ((u >> 16) & 1u)) >> 16;
}
__device__ __forceinline__ float lo16(u32 w) {
    union { u32 i; float f; } c; c.i = w << 16; return c.f;
}
__device__ __forceinline__ float hi16(u32 w) {
    union { u32 i; float f; } c; c.i = w & 0xFFFF0000u; return c.f;
}

// ---------------------------------------------------------------------------
// k_band: metrics over a horizontal band. nb bands/batch (32 fast, 1 slow).
// ---------------------------------------------------------------------------
__global__ __launch_bounds__(1024) void k_band(
    const float* __restrict__ ev, const float* __restrict__ fr,
    int nb, float* __restrict__ partials, float* __restrict__ z)
{
    __shared__ float sY[18][512];
    __shared__ float sE[18][512];
    __shared__ float cellPart[1024];
    __shared__ float cellFull[256];
    __shared__ float red[16][8];

    int blk = blockIdx.x;
    int b = blk / nb, band = blk % nb;
    int rowsPerBand = 512 / nb;
    int chunks = rowsPerBand >> 4;
    int rBase = band * rowsPerBand;
    int tid = threadIdx.x;

    const float* Pp = ev + (size_t)(b * 2)     * HW;
    const float* Np = ev + (size_t)(b * 2 + 1) * HW;
    const float* Rp = fr + (size_t)(b * 3)     * HW;
    const float* Gp = fr + (size_t)(b * 3 + 1) * HW;
    const float* Bp = fr + (size_t)(b * 3 + 2) * HW;

    if (nb == 1 && tid < 256) cellFull[tid] = 0.f;

    float aY = 0, aY2 = 0, aL = 0, aL2 = 0, aG = 0, aPb = 0, aLE = 0, aLE2 = 0;

    for (int ch = 0; ch < chunks; ++ch) {
        int r0 = rBase + ch * 16;
        for (int idx = tid; idx < 18 * 512; idx += 1024) {
            int rl = idx >> 9, c = idx & 511;
            int gy = r0 - 1 + rl;
            float y = 0.f, e = 0.f;
            if (gy >= 0 && gy < W512) {
                size_t o = (size_t)gy * W512 + c;
                float rr = Rp[o], gg = Gp[o], bb = Bp[o];
                y = fminf(fmaxf(0.299f * rr + 0.587f * gg + 0.114f * bb, 0.f), 1.f);
                e = fmaxf((Pp[o] + Np[o]) * (1.f / 255.f), 0.f);
            }
            sY[rl][c] = y; sE[rl][c] = e;
        }
        __syncthreads();

        float ce = 0.f;
        int hf = tid >> 9, col = tid & 511;
        for (int i = 0; i < 8; ++i) {
            int rl = hf + 2 * i;
            int lr = rl + 1;
            int gy = r0 + rl;
            float y   = sY[lr][col];
            float yu  = sY[lr - 1][col], yd = sY[lr + 1][col];
            float yl  = col        ? sY[lr][col - 1]     : 0.f;
            float yr  = col < 511  ? sY[lr][col + 1]     : 0.f;
            float yul = col        ? sY[lr - 1][col - 1] : 0.f;
            float yur = col < 511  ? sY[lr - 1][col + 1] : 0.f;
            float ydl = col        ? sY[lr + 1][col - 1] : 0.f;
            float ydr = col < 511  ? sY[lr + 1][col + 1] : 0.f;
            float lap = yu + yd + yl + yr - 4.f * y;
            float gx  = (yur + 2.f * yr + ydr) - (yul + 2.f * yl + ydl);
            float gy2 = (ydl + 2.f * yd + ydr) - (yul + 2.f * yu + yur);
            float gm  = sqrtf(gx * gx + gy2 * gy2);
            float e   = sE[lr][col];
            float el  = col       ? sE[lr][col - 1] : 0.f;
            float er  = col < 511 ? sE[lr][col + 1] : 0.f;
            float lapE = sE[lr - 1][col] + sE[lr + 1][col] + el + er - 4.f * e;
            size_t o = (size_t)gy * W512 + col;
            float pn = Pp[o] * (1.f / 255.f);
            float nn = Np[o] * (1.f / 255.f);
            float pb = (pn - nn) / (pn + nn + 1e-12f);
            aY += y; aY2 += y * y; aL += lap; aL2 += lap * lap; aG += gm;
            aPb += pb; aLE += lapE; aLE2 += lapE * lapE; ce += e;
        }
        cellPart[tid] = ce;
        __syncthreads();
        if (tid < 16) {
            float s = 0.f;
            int c0 = tid * 32;
            for (int h2 = 0; h2 < 2; ++h2)
                for (int c = 0; c < 32; ++c) s += cellPart[h2 * 512 + c0 + c];
            if (nb == 1) cellFull[(r0 >> 5) * 16 + tid] += s;
            else         partials[(size_t)blk * 32 + 9 + tid] = s;
        }
        __syncthreads();
    }

    float v[8] = {aY, aY2, aL, aL2, aG, aPb, aLE, aLE2};
    #pragma unroll
    for (int off = 32; off; off >>= 1)
        #pragma unroll
        for (int k = 0; k < 8; ++k) v[k] += __shfl_down(v[k], off);
    int lane = tid & 63, wid = tid >> 6;
    if (lane == 0)
        for (int k = 0; k < 8; ++k) red[wid][k] = v[k];
    __syncthreads();

    if (tid == 0) {
        float s[8];
        for (int k = 0; k < 8; ++k) {
            float t = 0.f;
            for (int w = 0; w < 16; ++w) t += red[w][k];
            s[k] = t;
        }
        if (nb > 1) {
            float* rec = partials + (size_t)blk * 32;
            for (int k = 0; k < 8; ++k) rec[k] = s[k];
        } else {
            float c1 = 0.f, c2 = 0.f, ct = 0.f;
            for (int j = 0; j < 256; ++j) {
                float m = cellFull[j] * (1.f / 1024.f);
                c1 += m; c2 += m * m; ct += cellFull[j];
            }
            const float FN = 262144.f;
            float muY   = s[0] / FN;
            float stdY  = sqrtf(fmaxf(s[1] / FN - muY * muY, 0.f));
            float varlp = fmaxf(s[3] - s[2] * s[2] / FN, 0.f) / (FN - 1.f);
            float gmean = s[4] / FN;
            float mc = c1 * (1.f / 256.f);
            float vc = fmaxf(c2 * (1.f / 256.f) - mc * mc, 0.f);
            float cv = sqrtf(vc) / (mc + 1e-12f);
            float dens = ct / FN;
            float pb = s[5] / FN;
            float varlpE = fmaxf(s[7] - s[6] * s[6] / FN, 0.f) / (FN - 1.f);
            float* zb = z + b * 8;
            zb[0] = muY; zb[1] = stdY; zb[2] = varlp; zb[3] = gmean;
            zb[4] = cv;  zb[5] = dens; zb[6] = pb;    zb[7] = varlpE;
        }
    }
}

// ---------------------------------------------------------------------------
// k_finalize (fast path): merge 32 band records per batch -> z[16][8]
// ---------------------------------------------------------------------------
__global__ __launch_bounds__(256) void k_finalize(
    const float* __restrict__ partials, float* __restrict__ z)
{
    __shared__ float sred[8];
    __shared__ float rr[4][3];
    int b = blockIdx.x, tid = threadIdx.x;
    if (tid < 8) {
        float s = 0.f;
        for (int band = 0; band < 32; ++band)
            s += partials[(size_t)(b * 32 + band) * 32 + tid];
        sred[tid] = s;
    }
    int cr = tid >> 4, cc = tid & 15;
    float cell = partials[(size_t)(b * 32 + 2 * cr)     * 32 + 9 + cc]
               + partials[(size_t)(b * 32 + 2 * cr + 1) * 32 + 9 + cc];
    float m = cell * (1.f / 1024.f);
    float c1 = m, c2 = m * m, ct = cell;
    #pragma unroll
    for (int off = 32; off; off >>= 1) {
        c1 += __shfl_down(c1, off);
        c2 += __shfl_down(c2, off);
        ct += __shfl_down(ct, off);
    }
    int lane = tid & 63, wid = tid >> 6;
    if (lane == 0) { rr[wid][0] = c1; rr[wid][1] = c2; rr[wid][2] = ct; }
    __syncthreads();
    if (tid == 0) {
        float C1 = rr[0][0] + rr[1][0] + rr[2][0] + rr[3][0];
        float C2 = rr[0][1] + rr[1][1] + rr[2][1] + rr[3][1];
        float CT = rr[0][2] + rr[1][2] + rr[2][2] + rr[3][2];
        const float FN = 262144.f;
        float muY   = sred[0] / FN;
        float stdY  = sqrtf(fmaxf(sred[1] / FN - muY * muY, 0.f));
        float varlp = fmaxf(sred[3] - sred[2] * sred[2] / FN, 0.f) / (FN - 1.f);
        float gmean = sred[4] / FN;
        float mc = C1 * (1.f / 256.f);
        float vc = fmaxf(C2 * (1.f / 256.f) - mc * mc, 0.f);
        float cv = sqrtf(vc) / (mc + 1e-12f);
        float dens = CT / FN;
        float pb = sred[5] / FN;
        float varlpE = fmaxf(sred[7] - sred[6] * sred[6] / FN, 0.f) / (FN - 1.f);
        float* zb = z + b * 8;
        zb[0] = muY; zb[1] = stdY; zb[2] = varlp; zb[3] = gmean;
        zb[4] = cv;  zb[5] = dens; zb[6] = pb;    zb[7] = varlpE;
    }
}

// ---------------------------------------------------------------------------
// k_mlp: metrics MLP -> coefs  +  BN-fold weights into global ws buffers
// (idle threads do the fold; k_main then reads them as wave-uniform scalar
//  loads — no LDS involvement). 1 block, (64,16) threads.
// ---------------------------------------------------------------------------
__global__ __launch_bounds__(1024) void k_mlp(
    const float* __restrict__ z,
    const float* __restrict__ w1, const float* __restrict__ b1,
    const float* __restrict__ w2, const float* __restrict__ b2,
    const float* __restrict__ hgw, const float* __restrict__ hgb,
    const float* __restrict__ hfw, const float* __restrict__ hfb,
    const float* __restrict__ rs,
    const float* __restrict__ c1w,
    const float* __restrict__ bn1g, const float* __restrict__ bn1b,
    const float* __restrict__ bn1m, const float* __restrict__ bn1v,
    const float* __restrict__ c2w,
    const float* __restrict__ bn2g, const float* __restrict__ bn2b,
    const float* __restrict__ bn2m, const float* __restrict__ bn2v,
    float* __restrict__ coefA, float* __restrict__ coefB,
    float* __restrict__ w1f, float* __restrict__ b1f,
    float* __restrict__ w2f, float* __restrict__ b2f)
{
    int j = threadIdx.x, b = threadIdx.y;
    int ft = b * 64 + j;   // flat 0..1023

    // ---- weight folding (independent of MLP work) ----
    if (ft < 720) {        // w1f[tap][oc16]
        int tap = ft >> 4, oc = ft & 15;
        float inv = bn1g[oc] * rsqrtf(bn1v[oc] + 1e-5f);
        w1f[ft] = c1w[oc * 45 + tap] * inv;
    }
    for (int t = ft; t < 1152; t += 1024) {   // w2f[tap144][oc8] (oc>=5 zero pad)
        int tap = t >> 3, oc = t & 7;
        float v = 0.f;
        if (oc < 5) {
            float inv = bn2g[oc] * rsqrtf(bn2v[oc] + 1e-5f);
            v = c2w[oc * 144 + tap] * inv;
        }
        w2f[t] = v;
    }
    if (ft < 16) {
        float inv = bn1g[ft] * rsqrtf(bn1v[ft] + 1e-5f);
        b1f[ft] = bn1b[ft] - bn1m[ft] * inv;
    }
    if (ft >= 32 && ft < 37) {
        int oc = ft - 32;
        float inv = bn2g[oc] * rsqrtf(bn2v[oc] + 1e-5f);
        b2f[oc] = bn2b[oc] - bn2m[oc] * inv;
    }

    // ---- MLP ----
    __shared__ float sZ[16][8], sH1[16][64], sH2[16][64], sG[16][2], sF[16][10];
    if (j < 8) sZ[b][j] = z[b * 8 + j];
    __syncthreads();
    float a = b1[j];
    #pragma unroll
    for (int k = 0; k < 8; ++k) a += sZ[b][k] * w1[j * 8 + k];
    sH1[b][j] = fmaxf(a, 0.f);
    __syncthreads();
    float a2 = b2[j];
    for (int k = 0; k < 64; ++k) a2 += sH1[b][k] * w2[j * 64 + k];
    sH2[b][j] = fmaxf(a2, 0.f);
    __syncthreads();
    if (j < 2) {
        float g = hgb[j];
        for (int k = 0; k < 64; ++k) g += sH2[b][k] * hgw[j * 64 + k];
        sG[b][j] = 1.f / (1.f + __expf(-g));
    }
    if (j < 10) {
        float f = hfb[j];
        for (int k = 0; k < 64; ++k) f += sH2[b][k] * hfw[j * 64 + k];
        sF[b][j] = f;
    }
    __syncthreads();
    if (j < 5) {
        float gs = sG[b][0] + sG[b][1] + 1e-12f;
        float alpha = (j < 2 ? sG[b][0] : sG[b][1]) / gs;
        float gamma = 1.f + 0.1f * sF[b][j];
        float beta  = 0.1f * sF[b][5 + j];
        float r = rs[0];
        coefA[b * 5 + j] = r * alpha * gamma;
        coefB[b * 5 + j] = r * alpha * beta;
    }
}

// ---------------------------------------------------------------------------
// k_main: fused conv1+bn1+silu+conv2+bn2 + FiLM + residual (f32 out).
// grid (16,16,16), 320 threads, 32x32 tile per block.
// Weights/biases are read from pre-folded GLOBAL buffers with wave-uniform
// indices -> compiler emits s_load into SGPRs (scalar pipe + K$), removing
// ~75% of the LDS instruction stream (the broadcast weight reads).
// LDS holds only the bf16-packed pixel tiles (36.2 KB).
// ---------------------------------------------------------------------------
__global__ __launch_bounds__(320, 5) void k_main(
    const float* __restrict__ ev, const float* __restrict__ fr,
    const float* __restrict__ w1f, const float* __restrict__ b1f,
    const float* __restrict__ w2f, const float* __restrict__ b2f,
    const float* __restrict__ coefA, const float* __restrict__ coefB,
    float* __restrict__ out)
{
    __shared__ u32 sIn[5][36][20];     // bf16-pair input tile, 14.4 KB
    __shared__ u32 sT1[8][34][20];     // bf16-pair conv1 half-output, 21.76 KB

    int tid = threadIdx.x;
    int b = blockIdx.z;
    int ty0 = blockIdx.y * 32, tx0 = blockIdx.x * 32;

    // stage input tile as bf16 pairs (3600 u32)
    for (int idx = tid; idx < 3600; idx += 320) {
        int chn = idx / 720, rem = idx % 720;
        int r = rem / 20, cc = rem % 20;
        int gy = ty0 - 2 + r, gx = tx0 - 2 + 2 * cc;
        float v0 = 0.f, v1 = 0.f;
        if (gy >= 0 && gy < W512 && 2 * cc < 36) {
            const float* src = (chn < 2) ? (ev + (size_t)(b * 2 + chn) * HW)
                                         : (fr + (size_t)(b * 3 + chn - 2) * HW);
            size_t o = (size_t)gy * W512;
            if (gx >= 0 && gx < W512)         v0 = src[o + gx];
            if (gx + 1 >= 0 && gx + 1 < W512) v1 = src[o + gx + 1];
        }
        sIn[chn][r][cc] = f2b_rtne(v0) | (f2b_rtne(v1) << 16);
    }
    __syncthreads();

    int pr = tid >> 3, pc0 = (tid & 7) << 2, pcu = (tid & 7) << 1;
    float acc2[5][4];
    #pragma unroll
    for (int oc = 0; oc < 5; ++oc) {
        float bb = b2f[oc];            // uniform -> SGPR
        #pragma unroll
        for (int p = 0; p < 4; ++p) acc2[oc][p] = bb;
    }

    #pragma unroll 1
    for (int h = 0; h < 2; ++h) {
        // ---- conv1 (+bn1+silu) for oc h*8..h*8+7, single pass (306<=320) ----
        if (tid < 306) {
            int r = tid / 9, cu = (tid % 9) * 2;
            float acc[8][4];
            #pragma unroll
            for (int oc = 0; oc < 8; ++oc) {
                float bb = b1f[h * 8 + oc];   // uniform -> SGPR
                #pragma unroll
                for (int p = 0; p < 4; ++p) acc[oc][p] = bb;
            }
            #pragma unroll 1
            for (int t = 0; t < 15; ++t) {
                const u32* rp = &sIn[t / 3][r + (t % 3)][cu];
                u32 q0 = rp[0], q1 = rp[1], q2 = rp[2];
                float x[6];
                x[0] = lo16(q0); x[1] = hi16(q0);
                x[2] = lo16(q1); x[3] = hi16(q1);
                x[4] = lo16(q2); x[5] = hi16(q2);
                #pragma unroll
                for (int dx = 0; dx < 3; ++dx) {
                    const float* wv = &w1f[(t * 3 + dx) * 16 + h * 8];  // uniform -> s_load
                    #pragma unroll
                    for (int oc = 0; oc < 8; ++oc) {
                        float w = wv[oc];
                        #pragma unroll
                        for (int p = 0; p < 4; ++p) acc[oc][p] += x[dx + p] * w;
                    }
                }
            }
            int gy1 = ty0 - 1 + r;
            bool rowok = (gy1 >= 0 && gy1 < W512);
            int c0 = cu * 2;
            #pragma unroll
            for (int oc = 0; oc < 8; ++oc) {
                float sl[4];
                #pragma unroll
                for (int p = 0; p < 4; ++p) {
                    float vv = acc[oc][p];
                    float s2 = vv / (1.f + __expf(-vv));
                    int gx1 = tx0 - 1 + c0 + p;
                    // conv2's SAME padding sees ZEROS outside image
                    if (!rowok || gx1 < 0 || gx1 >= W512) s2 = 0.f;
                    sl[p] = s2;
                }
                sT1[oc][r][cu]     = f2b_rtne(sl[0]) | (f2b_rtne(sl[1]) << 16);
                sT1[oc][r][cu + 1] = f2b_rtne(sl[2]) | (f2b_rtne(sl[3]) << 16);
            }
        }
        __syncthreads();

        // ---- conv2 partial accumulation over this half's 8 input channels ----
        if (tid < 256) {
            #pragma unroll 1
            for (int t = 0; t < 24; ++t) {          // t = ic*3 + dy
                const u32* rp = &sT1[t / 3][pr + (t % 3)][pcu];
                u32 q0 = rp[0], q1 = rp[1], q2 = rp[2];
                float x[6];
                x[0] = lo16(q0); x[1] = hi16(q0);
                x[2] = lo16(q1); x[3] = hi16(q1);
                x[4] = lo16(q2); x[5] = hi16(q2);
                #pragma unroll
                for (int dx = 0; dx < 3; ++dx) {
                    // uniform -> s_load (oc stride 8 => 32B aligned rows)
                    const float* wv = &w2f[(((h * 8 + t / 3) * 9 + (t % 3) * 3 + dx)) * 8];
                    #pragma unroll
                    for (int oc = 0; oc < 5; ++oc) {
                        float w = wv[oc];
                        #pragma unroll
                        for (int p = 0; p < 4; ++p) acc2[oc][p] += x[dx + p] * w;
                    }
                }
            }
        }
        __syncthreads();   // before next h overwrites sT1
    }

    if (tid < 256) {
        float cA[5], cB[5];
        #pragma unroll
        for (int oc = 0; oc < 5; ++oc) {
            cA[oc] = coefA[b * 5 + oc];   // uniform -> SGPR
            cB[oc] = coefB[b * 5 + oc];
        }
        int gy = ty0 + pr, gx0 = tx0 + pc0;
        #pragma unroll
        for (int oc = 0; oc < 5; ++oc) {
            size_t ioff;
            const float* src;
            if (oc < 2) { src = ev; ioff = (size_t)(b * 2 + oc) * HW; }
            else        { src = fr; ioff = (size_t)(b * 3 + oc - 2) * HW; }
            float4 iv = *reinterpret_cast<const float4*>(&src[ioff + (size_t)gy * W512 + gx0]);
            float4 pk;
            pk.x = iv.x + cA[oc] * acc2[oc][0] + cB[oc];
            pk.y = iv.y + cA[oc] * acc2[oc][1] + cB[oc];
            pk.z = iv.z + cA[oc] * acc2[oc][2] + cB[oc];
            pk.w = iv.w + cA[oc] * acc2[oc][3] + cB[oc];
            size_t off;
            if (oc < 2) off = (size_t)(b * 2 + oc) * HW + (size_t)gy * W512 + gx0;
            else        off = (size_t)2 * 16 * HW + (size_t)(b * 3 + oc - 2) * HW + (size_t)gy * W512 + gx0;
            *reinterpret_cast<float4*>(out + off) = pk;
        }
    }
}

// ---------------------------------------------------------------------------
extern "C" void kernel_launch(void* const* d_in, const int* in_sizes, int n_in,
                              void* d_out, int out_size, void* d_ws, size_t ws_size,
                              hipStream_t stream)
{
    const float* ev = (const float*)d_in[0];
    const float* fr = (const float*)d_in[1];

    float* ws = (float*)d_ws;
    float* coefA    = ws;            // 80
    float* coefB    = ws + 80;       // 80
    float* zbuf     = ws + 256;      // 128
    float* w1f      = ws + 512;      // 720  [tap45][oc16]
    float* b1f      = ws + 1232;     // 16
    float* w2f      = ws + 1248;     // 1152 [tap144][oc8]
    float* b2f      = ws + 2400;     // 5
    float* partials = ws + 2560;     // 16384 (fast path) -> total 75776 B

    bool fast = (ws_size >= 75776);
    int nb   = fast ? 32 : 1;
    int nblk = fast ? 512 : 16;
    k_band<<<dim3(nblk), dim3(1024), 0, stream>>>(ev, fr, nb, partials, zbuf);
    if (fast) k_finalize<<<dim3(16), dim3(256), 0, stream>>>(partials, zbuf);

    k_mlp<<<dim3(1), dim3(64, 16), 0, stream>>>(zbuf,
        (const float*)d_in[12], (const float*)d_in[13], (const float*)d_in[14], (const float*)d_in[15],
        (const float*)d_in[16], (const float*)d_in[17], (const float*)d_in[18], (const float*)d_in[19],
        (const float*)d_in[20],
        (const float*)d_in[2], (const float*)d_in[3], (const float*)d_in[4], (const float*)d_in[5],
        (const float*)d_in[6], (const float*)d_in[7], (const float*)d_in[8], (const float*)d_in[9],
        (const float*)d_in[10], (const float*)d_in[11],
        coefA, coefB, w1f, b1f, w2f, b2f);

    k_main<<<dim3(16, 16, 16), dim3(320), 0, stream>>>(ev, fr,
        w1f, b1f, w2f, b2f, coefA, coefB, (float*)d_out);
}